// Round 16
// baseline (329.525 us; speedup 1.0000x reference)
//
#include <hip/hip_runtime.h>

typedef unsigned short u16;
typedef unsigned int u32;
typedef __attribute__((ext_vector_type(8))) short short8;
typedef __attribute__((ext_vector_type(4))) float f32x4;

#define EPSV 1e-5f

__device__ __forceinline__ u16 f2bf(float f) {
    unsigned u = __float_as_uint(f);
    u += 0x7fffu + ((u >> 16) & 1u);
    return (u16)(u >> 16);
}

__device__ __forceinline__ f32x4 mfma_bf16(short8 a, short8 b, f32x4 c) {
    return __builtin_amdgcn_mfma_f32_16x16x32_bf16(a, b, c, 0, 0, 0);
}

__device__ __forceinline__ void gload_lds16(const void* g, void* l) {
    __builtin_amdgcn_global_load_lds((const __attribute__((address_space(1))) void*)g,
                                     (__attribute__((address_space(3))) void*)l, 16, 0, 0);
}

__device__ __forceinline__ u32 packgb(float g, float bt) {
    return (u32)f2bf(g) | ((u32)f2bf(bt) << 16);
}

// ---------------------------------------------------------------------------
// Prep 1: QKV weights bf16 [96][64] (rows 0-15 Q, 16-31 K, 32-95 V)
// ---------------------------------------------------------------------------
__global__ __launch_bounds__(256) void k_prep_qkv(
    const float* __restrict__ qw, const float* __restrict__ kw, const float* __restrict__ vw,
    u16* __restrict__ wq)
{
    const int tid = threadIdx.x;
#pragma unroll
    for (int i = 0; i < 24; i++) {
        int idx = tid + i * 256;
        int row = idx >> 6;
        float wv = (row < 16) ? qw[idx] : ((row < 32) ? kw[idx - 1024] : vw[idx - 2048]);
        wq[idx] = f2bf(wv);
    }
}

// ---------------------------------------------------------------------------
// Prep 2: lw bf16 [64][64] + packed lg/lbt u32 (into dead Vb region after pv)
// ---------------------------------------------------------------------------
__global__ __launch_bounds__(256) void k_prep_l(
    const float* __restrict__ lw, const float* __restrict__ lg, const float* __restrict__ lbt,
    u16* __restrict__ lwb, u32* __restrict__ lgb)
{
    const int tid = threadIdx.x;
#pragma unroll
    for (int i = 0; i < 16; i++) {
        int idx = tid + i * 256;
        lwb[idx] = f2bf(lw[idx]);
        lgb[idx] = packgb(lg[idx], lbt[idx]);
    }
}

// ---------------------------------------------------------------------------
// Kernel 1 (R14): fused QKV conv + bias + PReLU + per-head LN, 384 threads,
// wave w owns row-group mt=w; LN fully register-local.
// ---------------------------------------------------------------------------
__global__ __launch_bounds__(384) void k_qkv(
    const float* __restrict__ x, const u16* __restrict__ wq,
    const float* __restrict__ qb, const float* __restrict__ qa,
    const float* __restrict__ qg, const float* __restrict__ qbt,
    const float* __restrict__ kb, const float* __restrict__ ka,
    const float* __restrict__ kg, const float* __restrict__ kbt,
    const float* __restrict__ vb, const float* __restrict__ va,
    const float* __restrict__ vg, const float* __restrict__ vbt,
    u16* __restrict__ Qb, u16* __restrict__ Kb, u16* __restrict__ Vb)
{
    __shared__ u16 xT[64][66];
    __shared__ float bias_s[96], slope_s[96];

    const int tid = threadIdx.x, w = tid >> 6, lane = tid & 63;
    const int b = blockIdx.x >> 10, t = blockIdx.x & 1023;
    const int lc = lane & 15, grp = lane >> 4;

    if (tid < 96) {
        int row = tid; float bv, sv;
        if (row < 16)      { bv = qb[row];      sv = qa[row >> 2]; }
        else if (row < 32) { bv = kb[row - 16]; sv = ka[(row - 16) >> 2]; }
        else               { bv = vb[row - 32]; sv = va[(row - 32) >> 4]; }
        bias_s[row] = bv; slope_s[row] = sv;
    }
    const float* xbt = x + ((size_t)(b * 64) * 1024 + t) * 64;
    for (int chunk = tid; chunk < 1024; chunk += 384) {
        int c = chunk >> 4, q = chunk & 15;
        float4 v = *(const float4*)(xbt + (size_t)c * 65536 + q * 4);
        xT[q * 4 + 0][c] = f2bf(v.x);
        xT[q * 4 + 1][c] = f2bf(v.y);
        xT[q * 4 + 2][c] = f2bf(v.z);
        xT[q * 4 + 3][c] = f2bf(v.w);
    }
    __syncthreads();

    short8 af[2];
#pragma unroll
    for (int kt = 0; kt < 2; kt++)
        af[kt] = *(const short8*)(wq + (w * 16 + lc) * 64 + kt * 32 + grp * 8);

    f32x4 acc[4];
#pragma unroll
    for (int nt = 0; nt < 4; nt++) {
        f32x4 a = {0.f, 0.f, 0.f, 0.f};
        a = mfma_bf16(af[0], *(const short8*)(&xT[nt * 16 + lc][0 * 32 + grp * 8]), a);
        a = mfma_bf16(af[1], *(const short8*)(&xT[nt * 16 + lc][1 * 32 + grp * 8]), a);
        acc[nt] = a;
    }

#pragma unroll
    for (int nt = 0; nt < 4; nt++)
#pragma unroll
        for (int j = 0; j < 4; j++) {
            int row = w * 16 + grp * 4 + j;
            float y = acc[nt][j] + bias_s[row];
            acc[nt][j] = (y > 0.f) ? y : slope_s[row] * y;
        }

    if (w == 0) {
        float s = 0.f, ss = 0.f;
#pragma unroll
        for (int nt = 0; nt < 4; nt++)
#pragma unroll
            for (int j = 0; j < 4; j++) { float y = acc[nt][j]; s += y; ss += y * y; }
#pragma unroll
        for (int m = 1; m < 16; m <<= 1) { s += __shfl_xor(s, m, 64); ss += __shfl_xor(ss, m, 64); }
        float mu = s * (1.f / 256.f), var = ss * (1.f / 256.f) - mu * mu;
        float rs = rsqrtf(var + EPSV);
        size_t base = ((size_t)(grp * 8 + b) * 1024 + t) * 256;
#pragma unroll
        for (int nt = 0; nt < 4; nt++)
#pragma unroll
            for (int j = 0; j < 4; j++) {
                int gi = (grp * 4 + j) * 64 + nt * 16 + lc;
                float val = (acc[nt][j] - mu) * rs * qg[gi] + qbt[gi];
                Qb[base + j * 64 + nt * 16 + lc] = f2bf(val);
            }
    } else if (w == 1) {
        float s = 0.f, ss = 0.f;
#pragma unroll
        for (int nt = 0; nt < 4; nt++)
#pragma unroll
            for (int j = 0; j < 4; j++) { float y = acc[nt][j]; s += y; ss += y * y; }
#pragma unroll
        for (int m = 1; m < 16; m <<= 1) { s += __shfl_xor(s, m, 64); ss += __shfl_xor(ss, m, 64); }
        float mu = s * (1.f / 256.f), var = ss * (1.f / 256.f) - mu * mu;
        float rs = rsqrtf(var + EPSV);
        size_t base = ((size_t)(grp * 8 + b) * 1024 + t) * 256;
#pragma unroll
        for (int nt = 0; nt < 4; nt++)
#pragma unroll
            for (int j = 0; j < 4; j++) {
                int gi = (grp * 4 + j) * 64 + nt * 16 + lc;
                float val = (acc[nt][j] - mu) * rs * kg[gi] + kbt[gi];
                Kb[base + j * 64 + nt * 16 + lc] = f2bf(val);
            }
    } else {
        const int hv = w - 2;
        float s = 0.f, ss = 0.f;
#pragma unroll
        for (int nt = 0; nt < 4; nt++)
#pragma unroll
            for (int j = 0; j < 4; j++) { float y = acc[nt][j]; s += y; ss += y * y; }
#pragma unroll
        for (int m = 1; m < 64; m <<= 1) { s += __shfl_xor(s, m, 64); ss += __shfl_xor(ss, m, 64); }
        float mu = s * (1.f / 1024.f), var = ss * (1.f / 1024.f) - mu * mu;
        float rs = rsqrtf(var + EPSV);
        size_t base = ((size_t)(hv * 8 + b) * 1024 + t) * 1024;
#pragma unroll
        for (int nt = 0; nt < 4; nt++)
#pragma unroll
            for (int j = 0; j < 4; j++) {
                int gi = (hv * 16 + grp * 4 + j) * 64 + nt * 16 + lc;
                float val = (acc[nt][j] - mu) * rs * vg[gi] + vbt[gi];
                Vb[base + (grp * 4 + j) * 64 + nt * 16 + lc] = f2bf(val);
            }
    }
}

// ---------------------------------------------------------------------------
// Kernel 2 (fallback path): transpose V [n][s][d] -> Vt [n][d][s]
// ---------------------------------------------------------------------------
__global__ __launch_bounds__(256) void k_vtrans(const u16* __restrict__ Vb, u16* __restrict__ Vt)
{
    __shared__ u16 ts[64][72];
    const int tid = threadIdx.x;
    const int idx = blockIdx.x;
    const int n = idx >> 8, rest = idx & 255;
    const int s0 = (rest >> 4) * 64, d0 = (rest & 15) * 64;
    const size_t nb = (size_t)n << 20;

#pragma unroll
    for (int i = 0; i < 2; i++) {
        int chunk = tid + i * 256;
        int row = chunk >> 3, q = chunk & 7;
        uint4 v = *(const uint4*)(Vb + nb + (size_t)(s0 + row) * 1024 + d0 + q * 8);
        *(uint4*)(&ts[row][q * 8]) = v;
    }
    __syncthreads();
#pragma unroll
    for (int i = 0; i < 2; i++) {
        int chunk = tid + i * 256;
        int orow = chunk >> 3, q = chunk & 7;
        uint4 o;
        o.x = (unsigned)ts[q * 8 + 0][orow] | ((unsigned)ts[q * 8 + 1][orow] << 16);
        o.y = (unsigned)ts[q * 8 + 2][orow] | ((unsigned)ts[q * 8 + 3][orow] << 16);
        o.z = (unsigned)ts[q * 8 + 4][orow] | ((unsigned)ts[q * 8 + 5][orow] << 16);
        o.w = (unsigned)ts[q * 8 + 6][orow] | ((unsigned)ts[q * 8 + 7][orow] << 16);
        *(uint4*)(Vt + nb + (size_t)(d0 + orow) * 1024 + s0 + q * 8) = o;
    }
}

// ---------------------------------------------------------------------------
// Kernel 3 (fallback path): QK^T softmax -> P
// ---------------------------------------------------------------------------
__global__ __launch_bounds__(256) void k_attn(const u16* __restrict__ Qb, const u16* __restrict__ Kb,
                                              u16* __restrict__ P)
{
    __shared__ u16 Ks[4][16 * 256];
    __shared__ float red[2][4][16];

    const int bid = blockIdx.x;
    const int n = (bid & 7) + ((bid >> 9) << 3);
    const int qt = (bid >> 3) & 63;
    const int q0 = qt * 16;
    const int tid = threadIdx.x, w = tid >> 6, lane = tid & 63;
    const int grp = lane >> 4, lc = lane & 15;

    const u16* Qn = Qb + ((size_t)n << 18);
    const u16* Kn = Kb + ((size_t)n << 18);

    short8 qf[8];
#pragma unroll
    for (int kt = 0; kt < 8; kt++)
        qf[kt] = *(const short8*)(Qn + (size_t)(q0 + lc) * 256 + kt * 32 + grp * 8);

    u16* KsW = Ks[w];
    const int l_row = lane >> 5;
    const int l_cs = (lane & 31) * 8;

    f32x4 sacc[16];
#pragma unroll
    for (int st = 0; st < 16; st++) {
        int s0 = w * 256 + st * 16;
#pragma unroll
        for (int c = 0; c < 8; c++) {
            int row = c * 2 + l_row;
            int col = l_cs ^ ((row & 7) << 3);
            gload_lds16(Kn + (size_t)(s0 + row) * 256 + col, KsW + c * 512);
        }
        __syncthreads();
        f32x4 a = {0.f, 0.f, 0.f, 0.f};
#pragma unroll
        for (int kt = 0; kt < 8; kt++) {
            int off = lc * 256 + ((kt * 32 + grp * 8) ^ ((lc & 7) << 3));
            short8 kf = *(const short8*)(KsW + off);
            a = mfma_bf16(qf[kt], kf, a);
        }
        sacc[st] = a;
        __syncthreads();
    }

    float mx[4] = {-1e30f, -1e30f, -1e30f, -1e30f};
#pragma unroll
    for (int st = 0; st < 16; st++)
#pragma unroll
        for (int j = 0; j < 4; j++) {
            float v = sacc[st][j] * 0.0625f;
            sacc[st][j] = v;
            mx[j] = fmaxf(mx[j], v);
        }
#pragma unroll
    for (int m = 1; m < 16; m <<= 1)
#pragma unroll
        for (int j = 0; j < 4; j++) mx[j] = fmaxf(mx[j], __shfl_xor(mx[j], m, 64));

    if (lc == 0) {
#pragma unroll
        for (int j = 0; j < 4; j++) red[0][w][grp * 4 + j] = mx[j];
    }
    __syncthreads();
    float gm[4], sm[4] = {0.f, 0.f, 0.f, 0.f};
#pragma unroll
    for (int j = 0; j < 4; j++) {
        int row = grp * 4 + j;
        gm[j] = fmaxf(fmaxf(red[0][0][row], red[0][1][row]), fmaxf(red[0][2][row], red[0][3][row]));
    }
#pragma unroll
    for (int st = 0; st < 16; st++)
#pragma unroll
        for (int j = 0; j < 4; j++) {
            float p = __expf(sacc[st][j] - gm[j]);
            sacc[st][j] = p;
            sm[j] += p;
        }
#pragma unroll
    for (int m = 1; m < 16; m <<= 1)
#pragma unroll
        for (int j = 0; j < 4; j++) sm[j] += __shfl_xor(sm[j], m, 64);
    if (lc == 0) {
#pragma unroll
        for (int j = 0; j < 4; j++) red[1][w][grp * 4 + j] = sm[j];
    }
    __syncthreads();

    u16* Pn = P + ((size_t)n << 20);
    float inv[4];
#pragma unroll
    for (int j = 0; j < 4; j++) {
        int row = grp * 4 + j;
        float tot = red[1][0][row] + red[1][1][row] + red[1][2][row] + red[1][3][row];
        inv[j] = 1.f / tot;
    }
#pragma unroll
    for (int st = 0; st < 16; st++)
#pragma unroll
        for (int j = 0; j < 4; j++) {
            Pn[(size_t)(q0 + grp * 4 + j) * 1024 + w * 256 + st * 16 + lc] = f2bf(sacc[st][j] * inv[j]);
        }
}

// ---------------------------------------------------------------------------
// Kernel 2+3 FUSED (k_mid; used only when P does NOT alias Vb):
// blocks 0..2047 = attn -> P, blocks 2048..10239 = V transpose.
// ---------------------------------------------------------------------------
__global__ __launch_bounds__(256) void k_mid(
    const u16* __restrict__ Vb, u16* __restrict__ Vt,
    const u16* __restrict__ Qb, const u16* __restrict__ Kb, u16* __restrict__ P)
{
    __shared__ u16 smem[16640];            // 33280 B
    const int bid = blockIdx.x;
    const int tid = threadIdx.x;

    if (bid < 2048) {
        float* redf = (float*)(smem + 16384);
        u16 (*Ks)[16 * 256] = (u16(*)[16 * 256])smem;

        const int n = (bid & 7) + ((bid >> 9) << 3);
        const int qt = (bid >> 3) & 63;
        const int q0 = qt * 16;
        const int w = tid >> 6, lane = tid & 63;
        const int grp = lane >> 4, lc = lane & 15;

        const u16* Qn = Qb + ((size_t)n << 18);
        const u16* Kn = Kb + ((size_t)n << 18);

        short8 qf[8];
#pragma unroll
        for (int kt = 0; kt < 8; kt++)
            qf[kt] = *(const short8*)(Qn + (size_t)(q0 + lc) * 256 + kt * 32 + grp * 8);

        u16* KsW = Ks[w];
        const int l_row = lane >> 5;
        const int l_cs = (lane & 31) * 8;

        f32x4 sacc[16];
#pragma unroll
        for (int st = 0; st < 16; st++) {
            int s0 = w * 256 + st * 16;
#pragma unroll
            for (int c = 0; c < 8; c++) {
                int row = c * 2 + l_row;
                int col = l_cs ^ ((row & 7) << 3);
                gload_lds16(Kn + (size_t)(s0 + row) * 256 + col, KsW + c * 512);
            }
            __syncthreads();
            f32x4 a = {0.f, 0.f, 0.f, 0.f};
#pragma unroll
            for (int kt = 0; kt < 8; kt++) {
                int off = lc * 256 + ((kt * 32 + grp * 8) ^ ((lc & 7) << 3));
                short8 kf = *(const short8*)(KsW + off);
                a = mfma_bf16(qf[kt], kf, a);
            }
            sacc[st] = a;
            __syncthreads();
        }

        float mx[4] = {-1e30f, -1e30f, -1e30f, -1e30f};
#pragma unroll
        for (int st = 0; st < 16; st++)
#pragma unroll
            for (int j = 0; j < 4; j++) {
                float v = sacc[st][j] * 0.0625f;
                sacc[st][j] = v;
                mx[j] = fmaxf(mx[j], v);
            }
#pragma unroll
        for (int m = 1; m < 16; m <<= 1)
#pragma unroll
            for (int j = 0; j < 4; j++) mx[j] = fmaxf(mx[j], __shfl_xor(mx[j], m, 64));

        if (lc == 0) {
#pragma unroll
            for (int j = 0; j < 4; j++) redf[w * 16 + grp * 4 + j] = mx[j];
        }
        __syncthreads();
        float gm[4], sm[4] = {0.f, 0.f, 0.f, 0.f};
#pragma unroll
        for (int j = 0; j < 4; j++) {
            int row = grp * 4 + j;
            gm[j] = fmaxf(fmaxf(redf[0 * 16 + row], redf[1 * 16 + row]),
                          fmaxf(redf[2 * 16 + row], redf[3 * 16 + row]));
        }
#pragma unroll
        for (int st = 0; st < 16; st++)
#pragma unroll
            for (int j = 0; j < 4; j++) {
                float p = __expf(sacc[st][j] - gm[j]);
                sacc[st][j] = p;
                sm[j] += p;
            }
#pragma unroll
        for (int m = 1; m < 16; m <<= 1)
#pragma unroll
            for (int j = 0; j < 4; j++) sm[j] += __shfl_xor(sm[j], m, 64);
        if (lc == 0) {
#pragma unroll
            for (int j = 0; j < 4; j++) redf[64 + w * 16 + grp * 4 + j] = sm[j];
        }
        __syncthreads();

        u16* Pn = P + ((size_t)n << 20);
        float inv[4];
#pragma unroll
        for (int j = 0; j < 4; j++) {
            int row = grp * 4 + j;
            float tot = redf[64 + 0 * 16 + row] + redf[64 + 1 * 16 + row] +
                        redf[64 + 2 * 16 + row] + redf[64 + 3 * 16 + row];
            inv[j] = 1.f / tot;
        }
#pragma unroll
        for (int st = 0; st < 16; st++)
#pragma unroll
            for (int j = 0; j < 4; j++) {
                Pn[(size_t)(q0 + grp * 4 + j) * 1024 + w * 256 + st * 16 + lc] =
                    f2bf(sacc[st][j] * inv[j]);
            }
    } else {
        u16 (*ts)[72] = (u16(*)[72])smem;
        const int idx = bid - 2048;
        const int n = idx >> 8, rest = idx & 255;
        const int s0 = (rest >> 4) * 64, d0 = (rest & 15) * 64;
        const size_t nb = (size_t)n << 20;

#pragma unroll
        for (int i = 0; i < 2; i++) {
            int chunk = tid + i * 256;
            int row = chunk >> 3, q = chunk & 7;
            uint4 v = *(const uint4*)(Vb + nb + (size_t)(s0 + row) * 1024 + d0 + q * 8);
            *(uint4*)(&ts[row][q * 8]) = v;
        }
        __syncthreads();
#pragma unroll
        for (int i = 0; i < 2; i++) {
            int chunk = tid + i * 256;
            int orow = chunk >> 3, q = chunk & 7;
            uint4 o;
            o.x = (unsigned)ts[q * 8 + 0][orow] | ((unsigned)ts[q * 8 + 1][orow] << 16);
            o.y = (unsigned)ts[q * 8 + 2][orow] | ((unsigned)ts[q * 8 + 3][orow] << 16);
            o.z = (unsigned)ts[q * 8 + 4][orow] | ((unsigned)ts[q * 8 + 5][orow] << 16);
            o.w = (unsigned)ts[q * 8 + 6][orow] | ((unsigned)ts[q * 8 + 7][orow] << 16);
            *(uint4*)(Vt + nb + (size_t)(d0 + orow) * 1024 + s0 + q * 8) = o;
        }
    }
}

// ---------------------------------------------------------------------------
// Kernel 4: A = P x V per n. 256x256 tile, BK=32, 8 waves (2Mx4N).
// Triple-buffered stage-ahead-2, counted vmcnt + raw s_barrier.
// ---------------------------------------------------------------------------
__global__ __launch_bounds__(512, 1) void k_pv(const u16* __restrict__ P, const u16* __restrict__ Vt,
                                               float* __restrict__ outf, u16* __restrict__ outb,
                                               int use_bf16)
{
    __shared__ u16 lds[3][4][128 * 32];

    const int bid = blockIdx.x;
    const int n = (bid & 7) + ((bid >> 7) << 3);
    const int tile = (bid >> 3) & 15;
    const int tm = tile >> 2, tn = tile & 3;
    const int tid = threadIdx.x, w = tid >> 6, lane = tid & 63;
    const int wr = w >> 2, wc = w & 3;
    const int lc = lane & 15, grp = lane >> 4;

    const u16* Pa = P  + ((size_t)n << 20) + (size_t)tm * 256 * 1024;
    const u16* Va = Vt + ((size_t)n << 20) + (size_t)tn * 256 * 1024;

    const int srow = tid >> 2, scc = tid & 3;
    const int scol = (scc ^ (srow & 3)) * 8;
    const int ldst = w * 512;

    f32x4 acc[8][4];
#pragma unroll
    for (int mi = 0; mi < 8; mi++)
#pragma unroll
        for (int ni = 0; ni < 4; ni++) acc[mi][ni] = (f32x4){0.f, 0.f, 0.f, 0.f};

#define STAGE_PV(ks_, pb_)                                                        \
    {                                                                             \
        size_t k0_ = (size_t)(ks_) * 32;                                          \
        gload_lds16(Pa + (size_t)srow * 1024 + k0_ + scol,         &lds[pb_][0][ldst]); \
        gload_lds16(Pa + (size_t)(128 + srow) * 1024 + k0_ + scol, &lds[pb_][1][ldst]); \
        gload_lds16(Va + (size_t)srow * 1024 + k0_ + scol,         &lds[pb_][2][ldst]); \
        gload_lds16(Va + (size_t)(128 + srow) * 1024 + k0_ + scol, &lds[pb_][3][ldst]); \
    }

    STAGE_PV(0, 0);
    STAGE_PV(1, 1);
    asm volatile("s_waitcnt vmcnt(4)" ::: "memory");
    __builtin_amdgcn_s_barrier();

    const int rxor = (lc & 3);
    int cur = 0;
    for (int ks = 0; ks < 32; ks++) {
        int nxt = cur + 2; if (nxt >= 3) nxt -= 3;
        if (ks < 30) STAGE_PV(ks + 2, nxt);

        const u16* As = lds[cur][wr];
        const u16* Bs = lds[cur][2 + (wc >> 1)];
        const int brow0 = (wc & 1) * 64;

        short8 af[8], bf[4];
#pragma unroll
        for (int mi = 0; mi < 8; mi++)
            af[mi] = *(const short8*)(As + (mi * 16 + lc) * 32 + ((grp ^ rxor) * 8));
#pragma unroll
        for (int ni = 0; ni < 4; ni++)
            bf[ni] = *(const short8*)(Bs + (brow0 + ni * 16 + lc) * 32 + ((grp ^ rxor) * 8));

        __builtin_amdgcn_s_setprio(1);
#pragma unroll
        for (int mi = 0; mi < 8; mi++)
#pragma unroll
            for (int ni = 0; ni < 4; ni++)
                acc[mi][ni] = mfma_bf16(af[mi], bf[ni], acc[mi][ni]);
        __builtin_amdgcn_s_setprio(0);

        if (ks < 31) {
            if (ks < 30) {
                asm volatile("s_waitcnt vmcnt(4) lgkmcnt(0)" ::: "memory");
            } else {
                asm volatile("s_waitcnt vmcnt(0) lgkmcnt(0)" ::: "memory");
            }
            __builtin_amdgcn_s_barrier();
        }
        cur = (cur == 2) ? 0 : cur + 1;
    }
#undef STAGE_PV

    const int h = n >> 3, b = n & 7;
    if (use_bf16) {
#pragma unroll
        for (int mi = 0; mi < 8; mi++)
#pragma unroll
            for (int ni = 0; ni < 4; ni++) {
                int d = tn * 256 + wc * 64 + ni * 16 + lc;
                int c = h * 16 + (d >> 6), f = d & 63;
#pragma unroll
                for (int j = 0; j < 4; j++) {
                    int trow = tm * 256 + wr * 128 + mi * 16 + grp * 4 + j;
                    outb[(((size_t)b * 64 + c) * 1024 + trow) * 64 + f] = f2bf(acc[mi][ni][j]);
                }
            }
    } else {
#pragma unroll
        for (int mi = 0; mi < 8; mi++)
#pragma unroll
            for (int ni = 0; ni < 4; ni++) {
                int d = tn * 256 + wc * 64 + ni * 16 + lc;
                int c = h * 16 + (d >> 6), f = d & 63;
#pragma unroll
                for (int j = 0; j < 4; j++) {
                    int trow = tm * 256 + wr * 128 + mi * 16 + grp * 4 + j;
                    outf[(((size_t)b * 64 + c) * 1024 + trow) * 64 + f] = acc[mi][ni][j];
                }
            }
    }
}

// ---------------------------------------------------------------------------
// Kernel 5: final conv block + PReLU + LN(4096) + affine + residual.
// ---------------------------------------------------------------------------
__global__ __launch_bounds__(256, 2) void k_final(
    const float* __restrict__ Af, const u16* __restrict__ Ab, const float* __restrict__ x,
    const u16* __restrict__ lwbf, const u32* __restrict__ lgb,
    const float* __restrict__ lbias, const float* __restrict__ la,
    float* __restrict__ out, int use_bf16)
{
    __shared__ u16 AT[256][66];
    __shared__ u32 gb_s[64][66];
    __shared__ float bias_s[64];

    const int tid = threadIdx.x, w = tid >> 6, lane = tid & 63;
    const int b = blockIdx.x >> 8, tb = blockIdx.x & 255;
    const int t0 = tb * 4, t = t0 + w;
    const int lc = lane & 15, grp = lane >> 4;

    if (tid < 64) bias_s[tid] = lbias[tid];
#pragma unroll
    for (int i = 0; i < 16; i++) {
        int idx = tid + i * 256;
        gb_s[idx >> 6][idx & 63] = lgb[idx];
    }
    if (use_bf16) {
#pragma unroll
        for (int k = 0; k < 8; k++) {
            int idx = k * 256 + tid;
            int q = idx & 7, c = (idx >> 3) & 63, tl = idx >> 9;
            uint4 v = *(const uint4*)(Ab + ((size_t)(b * 64 + c) * 1024 + t0 + tl) * 64 + q * 8);
            const u16* pv = (const u16*)&v;
            int n = tl * 64 + q * 8;
#pragma unroll
            for (int i = 0; i < 8; i++) AT[n + i][c] = pv[i];
        }
    } else {
#pragma unroll
        for (int k = 0; k < 16; k++) {
            int idx = k * 256 + tid;
            int q = idx & 15, c = (idx >> 4) & 63, tl = idx >> 10;
            float4 v = *(const float4*)(Af + ((size_t)(b * 64 + c) * 1024 + t0 + tl) * 64 + q * 4);
            int n = tl * 64 + q * 4;
            AT[n + 0][c] = f2bf(v.x);
            AT[n + 1][c] = f2bf(v.y);
            AT[n + 2][c] = f2bf(v.z);
            AT[n + 3][c] = f2bf(v.w);
        }
    }
    __syncthreads();

    short8 bfr[4][2];
#pragma unroll
    for (int nt = 0; nt < 4; nt++)
#pragma unroll
        for (int kt = 0; kt < 2; kt++)
            bfr[nt][kt] = *(const short8*)(&AT[w * 64 + nt * 16 + lc][kt * 32 + grp * 8]);

    f32x4 acc[4][4];
#pragma unroll
    for (int mt = 0; mt < 4; mt++) {
        short8 af[2];
#pragma unroll
        for (int kt = 0; kt < 2; kt++)
            af[kt] = *(const short8*)(lwbf + (mt * 16 + lc) * 64 + kt * 32 + grp * 8);
#pragma unroll
        for (int nt = 0; nt < 4; nt++) {
            f32x4 a = {0.f, 0.f, 0.f, 0.f};
            a = mfma_bf16(af[0], bfr[nt][0], a);
            a = mfma_bf16(af[1], bfr[nt][1], a);
            acc[mt][nt] = a;
        }
    }

    const float slope = la[0];
    float s = 0.f, ss = 0.f;
#pragma unroll
    for (int mt = 0; mt < 4; mt++)
#pragma unroll
        for (int nt = 0; nt < 4; nt++)
#pragma unroll
            for (int j = 0; j < 4; j++) {
                float y = acc[mt][nt][j] + bias_s[mt * 16 + grp * 4 + j];
                y = (y > 0.f) ? y : slope * y;
                acc[mt][nt][j] = y;
                s += y; ss += y * y;
            }
#pragma unroll
    for (int m = 1; m < 64; m <<= 1) { s += __shfl_xor(s, m, 64); ss += __shfl_xor(ss, m, 64); }
    float mu = s * (1.f / 4096.f), var = ss * (1.f / 4096.f) - mu * mu;
    float rs = rsqrtf(var + EPSV);

#pragma unroll
    for (int mt = 0; mt < 4; mt++)
#pragma unroll
        for (int nt = 0; nt < 4; nt++)
#pragma unroll
            for (int j = 0; j < 4; j++) {
                int row = mt * 16 + grp * 4 + j, f = nt * 16 + lc;
                u32 p = gb_s[row][f];
                float g = __uint_as_float(p << 16), bt = __uint_as_float(p & 0xffff0000u);
                size_t gi = ((size_t)(b * 64 + row) * 1024 + t) * 64 + f;
                out[gi] = (acc[mt][nt][j] - mu) * rs * g + bt + x[gi];
            }
}

// ---------------------------------------------------------------------------
extern "C" void kernel_launch(void* const* d_in, const int* in_sizes, int n_in,
                              void* d_out, int out_size, void* d_ws, size_t ws_size,
                              hipStream_t stream)
{
    const float* x    = (const float*)d_in[0];
    const float* qw   = (const float*)d_in[1];
    const float* qb   = (const float*)d_in[2];
    const float* qa   = (const float*)d_in[3];
    const float* qg   = (const float*)d_in[4];
    const float* qbt  = (const float*)d_in[5];
    const float* kw   = (const float*)d_in[6];
    const float* kb   = (const float*)d_in[7];
    const float* ka   = (const float*)d_in[8];
    const float* kg   = (const float*)d_in[9];
    const float* kbt  = (const float*)d_in[10];
    const float* vw   = (const float*)d_in[11];
    const float* vb   = (const float*)d_in[12];
    const float* va   = (const float*)d_in[13];
    const float* vg   = (const float*)d_in[14];
    const float* vbt  = (const float*)d_in[15];
    const float* lw   = (const float*)d_in[16];
    const float* lb   = (const float*)d_in[17];
    const float* la   = (const float*)d_in[18];
    const float* lg   = (const float*)d_in[19];
    const float* lbt  = (const float*)d_in[20];

    float* out = (float*)d_out;

    // Scratch layout:
    //   ws[0   ..64MB) : Vb bf16 (fallback: later aliased by P); after pv: lwb/lgb
    //   ws[64MB..128MB): Vt bf16 ; first 12KB transiently hold wqkv
    //   ws[128MB..192MB): A bf16 (only if ws_size >= 192MB)
    //   d_out[0..16MB): Qb ; [16..32MB): Kb ; use_bf16 path: P at d_out[32..96MB)
    //   (k_pv w/ use_bf16 writes only Ab, so P in d_out survives until consumed;
    //    k_final then overwrites d_out after P is dead.)
    u16* Vb = (u16*)d_ws;
    u16* Vt = (u16*)((char*)d_ws + ((size_t)64 << 20));
    u16* Qb = (u16*)d_out;
    u16* Kb = (u16*)((char*)d_out + ((size_t)16 << 20));

    u16* wqkv = Vt;                             // [96][64] bf16, 12 KB
    u16* lwb  = (u16*)d_ws;                     // written after k_pv (Vb/P dead)
    u32* lgb  = (u32*)((char*)d_ws + 8192);

    const int use_bf16 = (ws_size >= ((size_t)192 << 20)) ? 1 : 0;
    u16* Ab = (u16*)((char*)d_ws + ((size_t)128 << 20));   // valid iff use_bf16

    k_prep_qkv<<<dim3(1), dim3(256), 0, stream>>>(qw, kw, vw, wqkv);
    k_qkv<<<dim3(8192), dim3(384), 0, stream>>>(x, wqkv, qb, qa, qg, qbt,
                                                kb, ka, kg, kbt,
                                                vb, va, vg, vbt, Qb, Kb, Vb);
    u16* P;
    if (use_bf16) {
        // P in d_out[32..96MB): no alias with Vb -> safe to fuse vtrans+attn
        P = (u16*)((char*)d_out + ((size_t)32 << 20));
        k_mid<<<dim3(10240), dim3(256), 0, stream>>>(Vb, Vt, Qb, Kb, P);
    } else {
        // P aliases Vb: must order vtrans (reads Vb) before attn (writes P)
        P = Vb;
        k_vtrans<<<dim3(8192), dim3(256), 0, stream>>>(Vb, Vt);
        k_attn<<<dim3(2048), dim3(256), 0, stream>>>(Qb, Kb, P);
    }
    k_pv<<<dim3(512), dim3(512), 0, stream>>>(P, Vt, out, Ab, use_bf16);
    k_prep_l<<<dim3(1), dim3(256), 0, stream>>>(lw, lg, lbt, lwb, lgb);
    k_final<<<dim3(2048), dim3(256), 0, stream>>>(out, Ab, x, lwb, lgb, lb, la, out, use_bf16);
}

// Round 17
// 314.240 us; speedup vs baseline: 1.0486x; 1.0486x over previous
//
#include <hip/hip_runtime.h>

typedef unsigned short u16;
typedef unsigned int u32;
typedef __attribute__((ext_vector_type(8))) short short8;
typedef __attribute__((ext_vector_type(4))) float f32x4;

#define EPSV 1e-5f

__device__ __forceinline__ u16 f2bf(float f) {
    unsigned u = __float_as_uint(f);
    u += 0x7fffu + ((u >> 16) & 1u);
    return (u16)(u >> 16);
}

__device__ __forceinline__ f32x4 mfma_bf16(short8 a, short8 b, f32x4 c) {
    return __builtin_amdgcn_mfma_f32_16x16x32_bf16(a, b, c, 0, 0, 0);
}

__device__ __forceinline__ void gload_lds16(const void* g, void* l) {
    __builtin_amdgcn_global_load_lds((const __attribute__((address_space(1))) void*)g,
                                     (__attribute__((address_space(3))) void*)l, 16, 0, 0);
}

__device__ __forceinline__ u32 packgb(float g, float bt) {
    return (u32)f2bf(g) | ((u32)f2bf(bt) << 16);
}

// ---------------------------------------------------------------------------
// Prep 1: QKV weights bf16 [96][64] (rows 0-15 Q, 16-31 K, 32-95 V)
// ---------------------------------------------------------------------------
__global__ __launch_bounds__(256) void k_prep_qkv(
    const float* __restrict__ qw, const float* __restrict__ kw, const float* __restrict__ vw,
    u16* __restrict__ wq)
{
    const int tid = threadIdx.x;
#pragma unroll
    for (int i = 0; i < 24; i++) {
        int idx = tid + i * 256;
        int row = idx >> 6;
        float wv = (row < 16) ? qw[idx] : ((row < 32) ? kw[idx - 1024] : vw[idx - 2048]);
        wq[idx] = f2bf(wv);
    }
}

// ---------------------------------------------------------------------------
// Prep 2 (after k_pv, into dead P region): lw bf16 [64][64] + packed lg/lbt u32
// ---------------------------------------------------------------------------
__global__ __launch_bounds__(256) void k_prep_l(
    const float* __restrict__ lw, const float* __restrict__ lg, const float* __restrict__ lbt,
    u16* __restrict__ lwb, u32* __restrict__ lgb)
{
    const int tid = threadIdx.x;
#pragma unroll
    for (int i = 0; i < 16; i++) {
        int idx = tid + i * 256;
        lwb[idx] = f2bf(lw[idx]);
        lgb[idx] = packgb(lg[idx], lbt[idx]);
    }
}

// ---------------------------------------------------------------------------
// Kernel 1: fused QKV conv + bias + PReLU + per-head LN. 384 threads, wave w
// owns row-group mt=w; LN register-local (R14-verified per-t algebra).
// NEW: 2 consecutive t's per block (one barrier per 2 t's, 512B-contiguous
// x-gather, 2x deeper load batching); compute phases use disjoint xT buffers.
// ---------------------------------------------------------------------------
__global__ __launch_bounds__(384) void k_qkv(
    const float* __restrict__ x, const u16* __restrict__ wq,
    const float* __restrict__ qb, const float* __restrict__ qa,
    const float* __restrict__ qg, const float* __restrict__ qbt,
    const float* __restrict__ kb, const float* __restrict__ ka,
    const float* __restrict__ kg, const float* __restrict__ kbt,
    const float* __restrict__ vb, const float* __restrict__ va,
    const float* __restrict__ vg, const float* __restrict__ vbt,
    u16* __restrict__ Qb, u16* __restrict__ Kb, u16* __restrict__ Vb)
{
    __shared__ u16 xT[2][64][66];   // [tl][f][c] bf16, 16.9 KB
    __shared__ float bias_s[96], slope_s[96];

    const int tid = threadIdx.x, w = tid >> 6, lane = tid & 63;
    const int b = blockIdx.x >> 9, tb = blockIdx.x & 511;   // 8 b x 512 tb
    const int t0 = tb * 2;
    const int lc = lane & 15, grp = lane >> 4;

    if (tid < 96) {
        int row = tid; float bv, sv;
        if (row < 16)      { bv = qb[row];      sv = qa[row >> 2]; }
        else if (row < 32) { bv = kb[row - 16]; sv = ka[(row - 16) >> 2]; }
        else               { bv = vb[row - 32]; sv = va[(row - 32) >> 4]; }
        bias_s[row] = bv; slope_s[row] = sv;
    }
    // stage x[b,:,t0:t0+2,:] transposed -> xT[tl][f][c]
    const float* xb0 = x + ((size_t)(b * 64) * 1024 + t0) * 64;
    for (int chunk = tid; chunk < 2048; chunk += 384) {
        int c = chunk >> 5, r = chunk & 31;
        int tl = r >> 4, q = r & 15;
        float4 v = *(const float4*)(xb0 + (size_t)c * 65536 + tl * 64 + q * 4);
        xT[tl][q * 4 + 0][c] = f2bf(v.x);
        xT[tl][q * 4 + 1][c] = f2bf(v.y);
        xT[tl][q * 4 + 2][c] = f2bf(v.z);
        xT[tl][q * 4 + 3][c] = f2bf(v.w);
    }
    __syncthreads();

    // weight fragments once (same rows both t's)
    short8 af[2];
#pragma unroll
    for (int kt = 0; kt < 2; kt++)
        af[kt] = *(const short8*)(wq + (w * 16 + lc) * 64 + kt * 32 + grp * 8);

#pragma unroll
    for (int tl = 0; tl < 2; tl++) {
        const int t = t0 + tl;

        f32x4 acc[4];
#pragma unroll
        for (int nt = 0; nt < 4; nt++) {
            f32x4 a = {0.f, 0.f, 0.f, 0.f};
            a = mfma_bf16(af[0], *(const short8*)(&xT[tl][nt * 16 + lc][0 * 32 + grp * 8]), a);
            a = mfma_bf16(af[1], *(const short8*)(&xT[tl][nt * 16 + lc][1 * 32 + grp * 8]), a);
            acc[nt] = a;
        }

#pragma unroll
        for (int nt = 0; nt < 4; nt++)
#pragma unroll
            for (int j = 0; j < 4; j++) {
                int row = w * 16 + grp * 4 + j;
                float y = acc[nt][j] + bias_s[row];
                acc[nt][j] = (y > 0.f) ? y : slope_s[row] * y;
            }

        if (w == 0) {
            float s = 0.f, ss = 0.f;
#pragma unroll
            for (int nt = 0; nt < 4; nt++)
#pragma unroll
                for (int j = 0; j < 4; j++) { float y = acc[nt][j]; s += y; ss += y * y; }
#pragma unroll
            for (int m = 1; m < 16; m <<= 1) { s += __shfl_xor(s, m, 64); ss += __shfl_xor(ss, m, 64); }
            float mu = s * (1.f / 256.f), var = ss * (1.f / 256.f) - mu * mu;
            float rs = rsqrtf(var + EPSV);
            size_t base = ((size_t)(grp * 8 + b) * 1024 + t) * 256;
#pragma unroll
            for (int nt = 0; nt < 4; nt++)
#pragma unroll
                for (int j = 0; j < 4; j++) {
                    int gi = (grp * 4 + j) * 64 + nt * 16 + lc;
                    float val = (acc[nt][j] - mu) * rs * qg[gi] + qbt[gi];
                    Qb[base + j * 64 + nt * 16 + lc] = f2bf(val);
                }
        } else if (w == 1) {
            float s = 0.f, ss = 0.f;
#pragma unroll
            for (int nt = 0; nt < 4; nt++)
#pragma unroll
                for (int j = 0; j < 4; j++) { float y = acc[nt][j]; s += y; ss += y * y; }
#pragma unroll
            for (int m = 1; m < 16; m <<= 1) { s += __shfl_xor(s, m, 64); ss += __shfl_xor(ss, m, 64); }
            float mu = s * (1.f / 256.f), var = ss * (1.f / 256.f) - mu * mu;
            float rs = rsqrtf(var + EPSV);
            size_t base = ((size_t)(grp * 8 + b) * 1024 + t) * 256;
#pragma unroll
            for (int nt = 0; nt < 4; nt++)
#pragma unroll
                for (int j = 0; j < 4; j++) {
                    int gi = (grp * 4 + j) * 64 + nt * 16 + lc;
                    float val = (acc[nt][j] - mu) * rs * kg[gi] + kbt[gi];
                    Kb[base + j * 64 + nt * 16 + lc] = f2bf(val);
                }
        } else {
            const int hv = w - 2;
            float s = 0.f, ss = 0.f;
#pragma unroll
            for (int nt = 0; nt < 4; nt++)
#pragma unroll
                for (int j = 0; j < 4; j++) { float y = acc[nt][j]; s += y; ss += y * y; }
#pragma unroll
            for (int m = 1; m < 64; m <<= 1) { s += __shfl_xor(s, m, 64); ss += __shfl_xor(ss, m, 64); }
            float mu = s * (1.f / 1024.f), var = ss * (1.f / 1024.f) - mu * mu;
            float rs = rsqrtf(var + EPSV);
            size_t base = ((size_t)(hv * 8 + b) * 1024 + t) * 1024;
#pragma unroll
            for (int nt = 0; nt < 4; nt++)
#pragma unroll
                for (int j = 0; j < 4; j++) {
                    int gi = (hv * 16 + grp * 4 + j) * 64 + nt * 16 + lc;
                    float val = (acc[nt][j] - mu) * rs * vg[gi] + vbt[gi];
                    Vb[base + (grp * 4 + j) * 64 + nt * 16 + lc] = f2bf(val);
                }
        }
    }
}

// ---------------------------------------------------------------------------
// Kernel 2: transpose V [n][s][d] -> Vt [n][d][s]  (64x64 tiles via LDS)
// ---------------------------------------------------------------------------
__global__ __launch_bounds__(256) void k_vtrans(const u16* __restrict__ Vb, u16* __restrict__ Vt)
{
    __shared__ u16 ts[64][72];
    const int tid = threadIdx.x;
    const int idx = blockIdx.x;
    const int n = idx >> 8, rest = idx & 255;
    const int s0 = (rest >> 4) * 64, d0 = (rest & 15) * 64;
    const size_t nb = (size_t)n << 20;

#pragma unroll
    for (int i = 0; i < 2; i++) {
        int chunk = tid + i * 256;
        int row = chunk >> 3, q = chunk & 7;
        uint4 v = *(const uint4*)(Vb + nb + (size_t)(s0 + row) * 1024 + d0 + q * 8);
        *(uint4*)(&ts[row][q * 8]) = v;
    }
    __syncthreads();
#pragma unroll
    for (int i = 0; i < 2; i++) {
        int chunk = tid + i * 256;
        int orow = chunk >> 3, q = chunk & 7;
        uint4 o;
        o.x = (unsigned)ts[q * 8 + 0][orow] | ((unsigned)ts[q * 8 + 1][orow] << 16);
        o.y = (unsigned)ts[q * 8 + 2][orow] | ((unsigned)ts[q * 8 + 3][orow] << 16);
        o.z = (unsigned)ts[q * 8 + 4][orow] | ((unsigned)ts[q * 8 + 5][orow] << 16);
        o.w = (unsigned)ts[q * 8 + 6][orow] | ((unsigned)ts[q * 8 + 7][orow] << 16);
        *(uint4*)(Vt + nb + (size_t)(d0 + orow) * 1024 + s0 + q * 8) = o;
    }
}

// ---------------------------------------------------------------------------
// Kernel 3: S = Q K^T / 16, row softmax, write normalized P bf16 [n][t][s].
// ---------------------------------------------------------------------------
__global__ __launch_bounds__(256) void k_attn(const u16* __restrict__ Qb, const u16* __restrict__ Kb,
                                              u16* __restrict__ P)
{
    __shared__ u16 Ks[4][16 * 256];
    __shared__ float red[2][4][16];

    const int bid = blockIdx.x;
    const int n = (bid & 7) + ((bid >> 9) << 3);
    const int qt = (bid >> 3) & 63;
    const int q0 = qt * 16;
    const int tid = threadIdx.x, w = tid >> 6, lane = tid & 63;
    const int grp = lane >> 4, lc = lane & 15;

    const u16* Qn = Qb + ((size_t)n << 18);
    const u16* Kn = Kb + ((size_t)n << 18);

    short8 qf[8];
#pragma unroll
    for (int kt = 0; kt < 8; kt++)
        qf[kt] = *(const short8*)(Qn + (size_t)(q0 + lc) * 256 + kt * 32 + grp * 8);

    u16* KsW = Ks[w];
    const int l_row = lane >> 5;
    const int l_cs = (lane & 31) * 8;

    f32x4 sacc[16];
#pragma unroll
    for (int st = 0; st < 16; st++) {
        int s0 = w * 256 + st * 16;
#pragma unroll
        for (int c = 0; c < 8; c++) {
            int row = c * 2 + l_row;
            int col = l_cs ^ ((row & 7) << 3);
            gload_lds16(Kn + (size_t)(s0 + row) * 256 + col, KsW + c * 512);
        }
        __syncthreads();
        f32x4 a = {0.f, 0.f, 0.f, 0.f};
#pragma unroll
        for (int kt = 0; kt < 8; kt++) {
            int off = lc * 256 + ((kt * 32 + grp * 8) ^ ((lc & 7) << 3));
            short8 kf = *(const short8*)(KsW + off);
            a = mfma_bf16(qf[kt], kf, a);
        }
        sacc[st] = a;
        __syncthreads();
    }

    float mx[4] = {-1e30f, -1e30f, -1e30f, -1e30f};
#pragma unroll
    for (int st = 0; st < 16; st++)
#pragma unroll
        for (int j = 0; j < 4; j++) {
            float v = sacc[st][j] * 0.0625f;
            sacc[st][j] = v;
            mx[j] = fmaxf(mx[j], v);
        }
#pragma unroll
    for (int m = 1; m < 16; m <<= 1)
#pragma unroll
        for (int j = 0; j < 4; j++) mx[j] = fmaxf(mx[j], __shfl_xor(mx[j], m, 64));

    if (lc == 0) {
#pragma unroll
        for (int j = 0; j < 4; j++) red[0][w][grp * 4 + j] = mx[j];
    }
    __syncthreads();
    float gm[4], sm[4] = {0.f, 0.f, 0.f, 0.f};
#pragma unroll
    for (int j = 0; j < 4; j++) {
        int row = grp * 4 + j;
        gm[j] = fmaxf(fmaxf(red[0][0][row], red[0][1][row]), fmaxf(red[0][2][row], red[0][3][row]));
    }
#pragma unroll
    for (int st = 0; st < 16; st++)
#pragma unroll
        for (int j = 0; j < 4; j++) {
            float p = __expf(sacc[st][j] - gm[j]);
            sacc[st][j] = p;
            sm[j] += p;
        }
#pragma unroll
    for (int m = 1; m < 16; m <<= 1)
#pragma unroll
        for (int j = 0; j < 4; j++) sm[j] += __shfl_xor(sm[j], m, 64);
    if (lc == 0) {
#pragma unroll
        for (int j = 0; j < 4; j++) red[1][w][grp * 4 + j] = sm[j];
    }
    __syncthreads();

    u16* Pn = P + ((size_t)n << 20);
    float inv[4];
#pragma unroll
    for (int j = 0; j < 4; j++) {
        int row = grp * 4 + j;
        float tot = red[1][0][row] + red[1][1][row] + red[1][2][row] + red[1][3][row];
        inv[j] = 1.f / tot;
    }
#pragma unroll
    for (int st = 0; st < 16; st++)
#pragma unroll
        for (int j = 0; j < 4; j++) {
            Pn[(size_t)(q0 + grp * 4 + j) * 1024 + w * 256 + st * 16 + lc] = f2bf(sacc[st][j] * inv[j]);
        }
}

// ---------------------------------------------------------------------------
// Kernel 4: A = P x V per n. 256x256 tile, BK=32, 8 waves (2Mx4N).
// Triple-buffered stage-ahead-2, counted vmcnt + raw s_barrier.
// Epilogue: fp32 (d_out) or bf16 (ws tail) per use_bf16.
// ---------------------------------------------------------------------------
__global__ __launch_bounds__(512, 1) void k_pv(const u16* __restrict__ P, const u16* __restrict__ Vt,
                                               float* __restrict__ outf, u16* __restrict__ outb,
                                               int use_bf16)
{
    __shared__ u16 lds[3][4][128 * 32];

    const int bid = blockIdx.x;
    const int n = (bid & 7) + ((bid >> 7) << 3);
    const int tile = (bid >> 3) & 15;
    const int tm = tile >> 2, tn = tile & 3;
    const int tid = threadIdx.x, w = tid >> 6, lane = tid & 63;
    const int wr = w >> 2, wc = w & 3;
    const int lc = lane & 15, grp = lane >> 4;

    const u16* Pa = P  + ((size_t)n << 20) + (size_t)tm * 256 * 1024;
    const u16* Va = Vt + ((size_t)n << 20) + (size_t)tn * 256 * 1024;

    const int srow = tid >> 2, scc = tid & 3;
    const int scol = (scc ^ (srow & 3)) * 8;
    const int ldst = w * 512;

    f32x4 acc[8][4];
#pragma unroll
    for (int mi = 0; mi < 8; mi++)
#pragma unroll
        for (int ni = 0; ni < 4; ni++) acc[mi][ni] = (f32x4){0.f, 0.f, 0.f, 0.f};

#define STAGE_PV(ks_, pb_)                                                        \
    {                                                                             \
        size_t k0_ = (size_t)(ks_) * 32;                                          \
        gload_lds16(Pa + (size_t)srow * 1024 + k0_ + scol,         &lds[pb_][0][ldst]); \
        gload_lds16(Pa + (size_t)(128 + srow) * 1024 + k0_ + scol, &lds[pb_][1][ldst]); \
        gload_lds16(Va + (size_t)srow * 1024 + k0_ + scol,         &lds[pb_][2][ldst]); \
        gload_lds16(Va + (size_t)(128 + srow) * 1024 + k0_ + scol, &lds[pb_][3][ldst]); \
    }

    STAGE_PV(0, 0);
    STAGE_PV(1, 1);
    asm volatile("s_waitcnt vmcnt(4)" ::: "memory");
    __builtin_amdgcn_s_barrier();

    const int rxor = (lc & 3);
    int cur = 0;
    for (int ks = 0; ks < 32; ks++) {
        int nxt = cur + 2; if (nxt >= 3) nxt -= 3;
        if (ks < 30) STAGE_PV(ks + 2, nxt);

        const u16* As = lds[cur][wr];
        const u16* Bs = lds[cur][2 + (wc >> 1)];
        const int brow0 = (wc & 1) * 64;

        short8 af[8], bf[4];
#pragma unroll
        for (int mi = 0; mi < 8; mi++)
            af[mi] = *(const short8*)(As + (mi * 16 + lc) * 32 + ((grp ^ rxor) * 8));
#pragma unroll
        for (int ni = 0; ni < 4; ni++)
            bf[ni] = *(const short8*)(Bs + (brow0 + ni * 16 + lc) * 32 + ((grp ^ rxor) * 8));

        __builtin_amdgcn_s_setprio(1);
#pragma unroll
        for (int mi = 0; mi < 8; mi++)
#pragma unroll
            for (int ni = 0; ni < 4; ni++)
                acc[mi][ni] = mfma_bf16(af[mi], bf[ni], acc[mi][ni]);
        __builtin_amdgcn_s_setprio(0);

        if (ks < 31) {
            if (ks < 30) {
                asm volatile("s_waitcnt vmcnt(4) lgkmcnt(0)" ::: "memory");
            } else {
                asm volatile("s_waitcnt vmcnt(0) lgkmcnt(0)" ::: "memory");
            }
            __builtin_amdgcn_s_barrier();
        }
        cur = (cur == 2) ? 0 : cur + 1;
    }
#undef STAGE_PV

    const int h = n >> 3, b = n & 7;
    if (use_bf16) {
#pragma unroll
        for (int mi = 0; mi < 8; mi++)
#pragma unroll
            for (int ni = 0; ni < 4; ni++) {
                int d = tn * 256 + wc * 64 + ni * 16 + lc;
                int c = h * 16 + (d >> 6), f = d & 63;
#pragma unroll
                for (int j = 0; j < 4; j++) {
                    int trow = tm * 256 + wr * 128 + mi * 16 + grp * 4 + j;
                    outb[(((size_t)b * 64 + c) * 1024 + trow) * 64 + f] = f2bf(acc[mi][ni][j]);
                }
            }
    } else {
#pragma unroll
        for (int mi = 0; mi < 8; mi++)
#pragma unroll
            for (int ni = 0; ni < 4; ni++) {
                int d = tn * 256 + wc * 64 + ni * 16 + lc;
                int c = h * 16 + (d >> 6), f = d & 63;
#pragma unroll
                for (int j = 0; j < 4; j++) {
                    int trow = tm * 256 + wr * 128 + mi * 16 + grp * 4 + j;
                    outf[(((size_t)b * 64 + c) * 1024 + trow) * 64 + f] = acc[mi][ni][j];
                }
            }
    }
}

// ---------------------------------------------------------------------------
// Kernel 5: final conv block + PReLU + LN(4096) + affine + residual.
// ---------------------------------------------------------------------------
__global__ __launch_bounds__(256, 2) void k_final(
    const float* __restrict__ Af, const u16* __restrict__ Ab, const float* __restrict__ x,
    const u16* __restrict__ lwbf, const u32* __restrict__ lgb,
    const float* __restrict__ lbias, const float* __restrict__ la,
    float* __restrict__ out, int use_bf16)
{
    __shared__ u16 AT[256][66];
    __shared__ u32 gb_s[64][66];
    __shared__ float bias_s[64];

    const int tid = threadIdx.x, w = tid >> 6, lane = tid & 63;
    const int b = blockIdx.x >> 8, tb = blockIdx.x & 255;
    const int t0 = tb * 4, t = t0 + w;
    const int lc = lane & 15, grp = lane >> 4;

    if (tid < 64) bias_s[tid] = lbias[tid];
#pragma unroll
    for (int i = 0; i < 16; i++) {
        int idx = tid + i * 256;
        gb_s[idx >> 6][idx & 63] = lgb[idx];
    }
    if (use_bf16) {
#pragma unroll
        for (int k = 0; k < 8; k++) {
            int idx = k * 256 + tid;
            int q = idx & 7, c = (idx >> 3) & 63, tl = idx >> 9;
            uint4 v = *(const uint4*)(Ab + ((size_t)(b * 64 + c) * 1024 + t0 + tl) * 64 + q * 8);
            const u16* pv = (const u16*)&v;
            int n = tl * 64 + q * 8;
#pragma unroll
            for (int i = 0; i < 8; i++) AT[n + i][c] = pv[i];
        }
    } else {
#pragma unroll
        for (int k = 0; k < 16; k++) {
            int idx = k * 256 + tid;
            int q = idx & 15, c = (idx >> 4) & 63, tl = idx >> 10;
            float4 v = *(const float4*)(Af + ((size_t)(b * 64 + c) * 1024 + t0 + tl) * 64 + q * 4);
            int n = tl * 64 + q * 4;
            AT[n + 0][c] = f2bf(v.x);
            AT[n + 1][c] = f2bf(v.y);
            AT[n + 2][c] = f2bf(v.z);
            AT[n + 3][c] = f2bf(v.w);
        }
    }
    __syncthreads();

    short8 bfr[4][2];
#pragma unroll
    for (int nt = 0; nt < 4; nt++)
#pragma unroll
        for (int kt = 0; kt < 2; kt++)
            bfr[nt][kt] = *(const short8*)(&AT[w * 64 + nt * 16 + lc][kt * 32 + grp * 8]);

    f32x4 acc[4][4];
#pragma unroll
    for (int mt = 0; mt < 4; mt++) {
        short8 af[2];
#pragma unroll
        for (int kt = 0; kt < 2; kt++)
            af[kt] = *(const short8*)(lwbf + (mt * 16 + lc) * 64 + kt * 32 + grp * 8);
#pragma unroll
        for (int nt = 0; nt < 4; nt++) {
            f32x4 a = {0.f, 0.f, 0.f, 0.f};
            a = mfma_bf16(af[0], bfr[nt][0], a);
            a = mfma_bf16(af[1], bfr[nt][1], a);
            acc[mt][nt] = a;
        }
    }

    const float slope = la[0];
    float s = 0.f, ss = 0.f;
#pragma unroll
    for (int mt = 0; mt < 4; mt++)
#pragma unroll
        for (int nt = 0; nt < 4; nt++)
#pragma unroll
            for (int j = 0; j < 4; j++) {
                float y = acc[mt][nt][j] + bias_s[mt * 16 + grp * 4 + j];
                y = (y > 0.f) ? y : slope * y;
                acc[mt][nt][j] = y;
                s += y; ss += y * y;
            }
#pragma unroll
    for (int m = 1; m < 64; m <<= 1) { s += __shfl_xor(s, m, 64); ss += __shfl_xor(ss, m, 64); }
    float mu = s * (1.f / 4096.f), var = ss * (1.f / 4096.f) - mu * mu;
    float rs = rsqrtf(var + EPSV);

#pragma unroll
    for (int mt = 0; mt < 4; mt++)
#pragma unroll
        for (int nt = 0; nt < 4; nt++)
#pragma unroll
            for (int j = 0; j < 4; j++) {
                int row = mt * 16 + grp * 4 + j, f = nt * 16 + lc;
                u32 p = gb_s[row][f];
                float g = __uint_as_float(p << 16), bt = __uint_as_float(p & 0xffff0000u);
                size_t gi = ((size_t)(b * 64 + row) * 1024 + t) * 64 + f;
                out[gi] = (acc[mt][nt][j] - mu) * rs * g + bt + x[gi];
            }
}

// ---------------------------------------------------------------------------
extern "C" void kernel_launch(void* const* d_in, const int* in_sizes, int n_in,
                              void* d_out, int out_size, void* d_ws, size_t ws_size,
                              hipStream_t stream)
{
    const float* x    = (const float*)d_in[0];
    const float* qw   = (const float*)d_in[1];
    const float* qb   = (const float*)d_in[2];
    const float* qa   = (const float*)d_in[3];
    const float* qg   = (const float*)d_in[4];
    const float* qbt  = (const float*)d_in[5];
    const float* kw   = (const float*)d_in[6];
    const float* kb   = (const float*)d_in[7];
    const float* ka   = (const float*)d_in[8];
    const float* kg   = (const float*)d_in[9];
    const float* kbt  = (const float*)d_in[10];
    const float* vw   = (const float*)d_in[11];
    const float* vb   = (const float*)d_in[12];
    const float* va   = (const float*)d_in[13];
    const float* vg   = (const float*)d_in[14];
    const float* vbt  = (const float*)d_in[15];
    const float* lw   = (const float*)d_in[16];
    const float* lb   = (const float*)d_in[17];
    const float* la   = (const float*)d_in[18];
    const float* lg   = (const float*)d_in[19];
    const float* lbt  = (const float*)d_in[20];

    float* out = (float*)d_out;

    // Scratch layout (R14-proven):
    //   ws[0   ..64MB) : Vb bf16 ; later aliased by P ; after k_pv: lwb/lgb tables
    //   ws[64MB..128MB): Vt bf16 ; first 12KB transiently hold wqkv
    //   ws[128MB..192MB): A bf16 (only if ws_size >= 192MB; else A fp32 in d_out)
    //   d_out[0..16MB) : Qb ; [16..32MB): Kb (dead before A lands in d_out)
    u16* Vb = (u16*)d_ws;
    u16* Vt = (u16*)((char*)d_ws + ((size_t)64 << 20));
    u16* P  = Vb;
    u16* Qb = (u16*)d_out;
    u16* Kb = (u16*)((char*)d_out + ((size_t)16 << 20));

    u16* wqkv = Vt;                             // [96][64] bf16, 12 KB
    u16* lwb  = (u16*)d_ws;                     // written after k_pv (P region dead)
    u32* lgb  = (u32*)((char*)d_ws + 8192);

    const int use_bf16 = (ws_size >= ((size_t)192 << 20)) ? 1 : 0;
    u16* Ab = (u16*)((char*)d_ws + ((size_t)128 << 20));   // valid iff use_bf16

    k_prep_qkv<<<dim3(1), dim3(256), 0, stream>>>(qw, kw, vw, wqkv);
    k_qkv<<<dim3(4096), dim3(384), 0, stream>>>(x, wqkv, qb, qa, qg, qbt,
                                                kb, ka, kg, kbt,
                                                vb, va, vg, vbt, Qb, Kb, Vb);
    k_vtrans<<<dim3(8192), dim3(256), 0, stream>>>(Vb, Vt);
    k_attn<<<dim3(2048), dim3(256), 0, stream>>>(Qb, Kb, P);
    k_pv<<<dim3(512), dim3(512), 0, stream>>>(P, Vt, out, Ab, use_bf16);
    k_prep_l<<<dim3(1), dim3(256), 0, stream>>>(lw, lg, lbt, lwb, lgb);
    k_final<<<dim3(2048), dim3(256), 0, stream>>>(out, Ab, x, lwb, lgb, lb, la, out, use_bf16);
}